// Round 2
// baseline (10357.612 us; speedup 1.0000x reference)
//
#include <hip/hip_runtime.h>
#include <cstddef>

// Problem constants
#define BATCH 64
#define SEQL  512
#define IDIM  256
#define HDIM  256
#define G7    1792            // 7*H
#define OSTRIDE (64*513*256)  // per-output-tensor elements = 8,404,992
#define XG_ELEMS ((size_t)BATCH*SEQL*G7)       // 58,720,256
#define XG_BYTES (XG_ELEMS*4)                  // 234,881,024
// ws layout: [xg | hx(2*64*2*128 floats) | counters(64 ints)]
#define HX_FLOATS (2*64*2*128)                 // 32768 floats = 128 KB
#define HX_PAR_STRIDE (64*2*128)               // 16384 floats per parity

// ---------------------------------------------------------------------------
// Kernel 1: zero-fill d_out (harness poisons it to 0xAA before every launch;
// masked steps and the t=0 row must be exactly 0).
// ---------------------------------------------------------------------------
__global__ void zero_out(float4* __restrict__ p, int n4) {
    int i = blockIdx.x * blockDim.x + threadIdx.x;
    int stride = gridDim.x * blockDim.x;
    for (; i < n4; i += stride) p[i] = make_float4(0.f, 0.f, 0.f, 0.f);
}

// Tiny kernel: zero the 64 pair-handshake counters (ws is poisoned each launch)
__global__ void zero_sync(int* __restrict__ c) { c[threadIdx.x] = 0; }

// ---------------------------------------------------------------------------
// Kernel 2: xg = x @ Wx^T + bx   (M=32768, N=1792, K=256), fp32 LDS-tiled.
// Skips M-tiles whose whole 128-row t-range is masked out.
// ---------------------------------------------------------------------------
__global__ __launch_bounds__(256) void gemm_xg(const float* __restrict__ X,
                                               const float* __restrict__ W,
                                               const float* __restrict__ bx,
                                               const int* __restrict__ seq_lens,
                                               float* __restrict__ xg) {
    __shared__ float As[8][132];
    __shared__ float Bs[8][132];
    const int m0 = blockIdx.y * 128;
    const int n0 = blockIdx.x * 128;
    const int b  = m0 >> 9;             // 512 rows per batch, 128 | 512
    if ((m0 & 511) >= seq_lens[b]) return;   // fully-masked tile: dead

    const int tid = threadIdx.x;
    const int lr  = tid >> 1;           // 0..127 row in tile
    const int lc  = (tid & 1) << 2;     // k sub-offset 0 or 4
    const int tx  = tid & 15;
    const int ty  = tid >> 4;

    const float* Aptr = X + (size_t)(m0 + lr) * 256 + lc;
    const float* Bptr = W + (size_t)(n0 + lr) * 256 + lc;

    float acc[8][8] = {};

    for (int k0 = 0; k0 < 256; k0 += 8) {
        float4 av = *(const float4*)(Aptr + k0);
        float4 bv = *(const float4*)(Bptr + k0);
        __syncthreads();
        As[lc + 0][lr] = av.x; As[lc + 1][lr] = av.y;
        As[lc + 2][lr] = av.z; As[lc + 3][lr] = av.w;
        Bs[lc + 0][lr] = bv.x; Bs[lc + 1][lr] = bv.y;
        Bs[lc + 2][lr] = bv.z; Bs[lc + 3][lr] = bv.w;
        __syncthreads();
#pragma unroll
        for (int kk = 0; kk < 8; ++kk) {
            float a[8], bb[8];
#pragma unroll
            for (int i = 0; i < 8; ++i) a[i] = As[kk][ty * 8 + i];
#pragma unroll
            for (int jj = 0; jj < 8; ++jj) bb[jj] = Bs[kk][tx * 8 + jj];
#pragma unroll
            for (int i = 0; i < 8; ++i)
#pragma unroll
                for (int jj = 0; jj < 8; ++jj) acc[i][jj] += a[i] * bb[jj];
        }
    }

    float bxa[8];
#pragma unroll
    for (int jj = 0; jj < 8; ++jj) bxa[jj] = bx[n0 + tx * 8 + jj];
#pragma unroll
    for (int i = 0; i < 8; ++i) {
        float* orow = xg + (size_t)(m0 + ty * 8 + i) * G7 + n0 + tx * 8;
        float4 v0 = make_float4(acc[i][0] + bxa[0], acc[i][1] + bxa[1],
                                acc[i][2] + bxa[2], acc[i][3] + bxa[3]);
        float4 v1 = make_float4(acc[i][4] + bxa[4], acc[i][5] + bxa[5],
                                acc[i][6] + bxa[6], acc[i][7] + bxa[7]);
        *(float4*)(orow)     = v0;
        *(float4*)(orow + 4) = v1;
    }
}

// ---------------------------------------------------------------------------
// Kernel 3: CT-LSTM recurrence with REGISTER-RESIDENT weights.
// 2 blocks per batch, split by h-index: block (b,s) owns h-indices
// [s*128, s*128+128) and the 896 gate rows {g*256 + s*128 + ii, g=0..6}.
// Thread j (0..895): gate g=j>>7, ii=j&127, row=g*256+s*128+ii.
// Weights for the row live in 64 float4 VGPRs (loaded once, statically
// indexed). Per step: matvec from LDS-broadcast h, activation, local h/c
// update (threads 0..127), pair h-slice exchange via agent-scope atomics.
// ---------------------------------------------------------------------------
__global__ __launch_bounds__(896, 1) void ctlstm_rec2(
    const float* __restrict__ xg, const float* __restrict__ dt,
    const int* __restrict__ seq_lens, const float* __restrict__ Wh,
    const float* __restrict__ bh, float* __restrict__ hx,
    int* __restrict__ cnt, float* __restrict__ out)
{
    __shared__ float h_lds[256];
    __shared__ float g_lds[896];

    const int b  = blockIdx.x >> 1;
    const int s  = blockIdx.x & 1;
    const int j  = threadIdx.x;
    const int g  = j >> 7;            // 0..6, uniform per wave (128 = 2 waves)
    const int ii = j & 127;
    const int row = g * 256 + s * 128 + ii;
    const int sl = seq_lens[b];

    // One-time weight load into registers (statically indexed -> VGPRs)
    const float* wr = Wh + (size_t)row * 256;
    float4 wv[64];
#pragma unroll
    for (int k4 = 0; k4 < 64; ++k4) wv[k4] = *(const float4*)(wr + 4 * k4);

    const float bhr = bh[row];
    if (j < 256) h_lds[j] = 0.f;
    float cn = 0.f;                               // c state, valid for j<128
    __syncthreads();

    for (int t = 0; t < sl; ++t) {
        // ---- matvec: acc = xg[b][t][row] + bh[row] + sum_k W[row][k]*h[k]
        float acc = xg[((size_t)b * SEQL + t) * G7 + row] + bhr;
#pragma unroll
        for (int k4 = 0; k4 < 64; ++k4) {
            float4 h4 = *(const float4*)&h_lds[4 * k4];
            acc = fmaf(wv[k4].x, h4.x, acc);
            acc = fmaf(wv[k4].y, h4.y, acc);
            acc = fmaf(wv[k4].z, h4.z, acc);
            acc = fmaf(wv[k4].w, h4.w, acc);
        }
        // ---- activation (g uniform per wave: no divergence)
        float act;
        if (g == 2)      act = tanhf(acc);
        else if (g == 4) act = fmaxf(acc, 0.f) + log1pf(expf(-fabsf(acc)));
        else             act = 1.f / (1.f + expf(-acc));
        g_lds[j] = act;
        __syncthreads();

        const int par = t & 1;
        if (j < 128) {
            float iv  = g_lds[j];
            float fv  = g_lds[128 + j];
            float zv  = g_lds[256 + j];
            float ov  = g_lds[384 + j];
            float dv  = g_lds[512 + j];
            float ibv = g_lds[640 + j];
            float fbv = g_lds[768 + j];

            float c   = fv * cn + iv * zv;
            float hh  = ov * tanhf(c);
            float cb  = fbv * cn + ibv * zv;
            float dtv = dt[b * SEQL + t];
            float ct  = cb + (c - cb) * expf(-dv * dtv);
            float ht  = ov * tanhf(ct);
            cn = ct;

            size_t base = ((size_t)b * 513 + t + 1) * 256 + s * 128 + j;
            out[base]                       = ht;   // hn2
            out[(size_t)OSTRIDE + base]     = hh;   // masked h
            out[2 * (size_t)OSTRIDE + base] = c;    // masked c
            out[3 * (size_t)OSTRIDE + base] = cb;   // masked c_bar
            out[4 * (size_t)OSTRIDE + base] = ov;   // masked o
            out[5 * (size_t)OSTRIDE + base] = dv;   // masked d

            h_lds[s * 128 + j] = ht;
            // publish own slice (agent scope -> coherent across XCDs)
            __hip_atomic_store(&hx[(size_t)par * HX_PAR_STRIDE +
                                   ((size_t)b * 2 + s) * 128 + j],
                               ht, __ATOMIC_RELAXED, __HIP_MEMORY_SCOPE_AGENT);
        }
        __syncthreads();   // compiler drains vmcnt before s_barrier -> stores done

        if (j == 0) {
            __hip_atomic_fetch_add(&cnt[b], 1, __ATOMIC_RELEASE,
                                   __HIP_MEMORY_SCOPE_AGENT);
            while (__hip_atomic_load(&cnt[b], __ATOMIC_ACQUIRE,
                                     __HIP_MEMORY_SCOPE_AGENT) < 2 * (t + 1)) {}
        }
        __syncthreads();

        if (j < 128) {
            float hv = __hip_atomic_load(&hx[(size_t)par * HX_PAR_STRIDE +
                                             ((size_t)b * 2 + (1 - s)) * 128 + j],
                                         __ATOMIC_RELAXED, __HIP_MEMORY_SCOPE_AGENT);
            h_lds[(1 - s) * 128 + j] = hv;
        }
        __syncthreads();
    }
}

// ---------------------------------------------------------------------------
extern "C" void kernel_launch(void* const* d_in, const int* in_sizes, int n_in,
                              void* d_out, int out_size, void* d_ws, size_t ws_size,
                              hipStream_t stream) {
    const float* x   = (const float*)d_in[0];
    const float* dt  = (const float*)d_in[1];
    const int*   sl  = (const int*)d_in[2];
    const float* Wx  = (const float*)d_in[3];
    const float* bx  = (const float*)d_in[4];
    const float* Wh  = (const float*)d_in[5];
    const float* bh  = (const float*)d_in[6];
    float* out = (float*)d_out;

    float* xg  = (float*)d_ws;
    float* hx  = (float*)((char*)d_ws + XG_BYTES);
    int*   cnt = (int*)((char*)d_ws + XG_BYTES + (size_t)HX_FLOATS * 4);

    // 0: zero handshake counters (ws poisoned 0xAA each launch)
    zero_sync<<<1, 64, 0, stream>>>(cnt);

    // 1: zero-fill output (poisoned 0xAA each launch)
    int n4 = out_size / 4;   // out_size = 50,466,816 (divisible by 4)
    zero_out<<<2048, 256, 0, stream>>>((float4*)out, n4);

    // 2: input GEMM xg = x @ Wx^T + bx   (masked tiles skipped)
    dim3 ggrid(G7 / 128, (BATCH * SEQL) / 128);   // 14 x 256
    gemm_xg<<<ggrid, 256, 0, stream>>>(x, Wx, bx, sl, xg);

    // 3: recurrence: 2 blocks per batch, register-resident weights
    ctlstm_rec2<<<BATCH * 2, 896, 0, stream>>>(xg, dt, sl, Wh, bh, hx, cnt, out);
}

// Round 3
// 3332.213 us; speedup vs baseline: 3.1083x; 3.1083x over previous
//
#include <hip/hip_runtime.h>
#include <cstddef>
#include <cstdint>

// Problem constants
#define BATCH 64
#define SEQL  512
#define G7    1792            // 7*H
#define OSTRIDE (64*513*256)  // per-output-tensor elements
#define XG_BYTES ((size_t)BATCH*SEQL*G7*4)     // 234,881,024
// ws layout: [xg | hx (2*64*4*64 floats = 128KB) | cnt (256B) | Wp16 (918KB)]
#define HX_OFF   XG_BYTES
#define HX_BYTES ((size_t)2*64*4*64*4)
#define CNT_OFF  (HX_OFF + HX_BYTES)
#define WP_OFF   (CNT_OFF + 256)
#define HX_PAR   16384        // floats per parity buffer

typedef _Float16 f16x2 __attribute__((ext_vector_type(2)));
union U32H2 { uint32_t u; f16x2 h; };

__device__ __forceinline__ float fd2(uint32_t w, uint32_t h, float c) {
    U32H2 a; a.u = w; U32H2 b; b.u = h;
    return __builtin_amdgcn_fdot2(a.h, b.h, c, false);
}

// ---------------------------------------------------------------------------
__global__ void zero_out(float4* __restrict__ p, int n4) {
    int i = blockIdx.x * blockDim.x + threadIdx.x;
    int stride = gridDim.x * blockDim.x;
    for (; i < n4; i += stride) p[i] = make_float4(0.f, 0.f, 0.f, 0.f);
}

__global__ void zero_sync(int* __restrict__ c) { c[threadIdx.x] = 0; }

// ---------------------------------------------------------------------------
// Pack Wh (7H x H fp32) -> fp16, layout uint4 Wp[c][row]: chunk c holds
// k = 8c..8c+7 as 4 packed half2. Coalesced one-time loads in the recurrence.
// ---------------------------------------------------------------------------
__global__ __launch_bounds__(256) void pack_wh16(const float* __restrict__ Wh,
                                                 uint4* __restrict__ Wp) {
    int idx = blockIdx.x * 256 + threadIdx.x;    // 0 .. 57343
    if (idx >= 1792 * 32) return;
    int r = idx % 1792;
    int c = idx / 1792;
    const float* src = Wh + (size_t)r * 256 + c * 8;
    uint32_t w[4];
#pragma unroll
    for (int j = 0; j < 4; ++j) {
        U32H2 t;
        t.h[0] = (_Float16)src[2 * j];
        t.h[1] = (_Float16)src[2 * j + 1];
        w[j] = t.u;
    }
    Wp[(size_t)c * 1792 + r] = make_uint4(w[0], w[1], w[2], w[3]);
}

// ---------------------------------------------------------------------------
// Kernel 2: xg = x @ Wx^T + bx   (unchanged from round 1)
// ---------------------------------------------------------------------------
__global__ __launch_bounds__(256) void gemm_xg(const float* __restrict__ X,
                                               const float* __restrict__ W,
                                               const float* __restrict__ bx,
                                               const int* __restrict__ seq_lens,
                                               float* __restrict__ xg) {
    __shared__ float As[8][132];
    __shared__ float Bs[8][132];
    const int m0 = blockIdx.y * 128;
    const int n0 = blockIdx.x * 128;
    const int b  = m0 >> 9;
    if ((m0 & 511) >= seq_lens[b]) return;

    const int tid = threadIdx.x;
    const int lr  = tid >> 1;
    const int lc  = (tid & 1) << 2;
    const int tx  = tid & 15;
    const int ty  = tid >> 4;

    const float* Aptr = X + (size_t)(m0 + lr) * 256 + lc;
    const float* Bptr = W + (size_t)(n0 + lr) * 256 + lc;

    float acc[8][8] = {};

    for (int k0 = 0; k0 < 256; k0 += 8) {
        float4 av = *(const float4*)(Aptr + k0);
        float4 bv = *(const float4*)(Bptr + k0);
        __syncthreads();
        As[lc + 0][lr] = av.x; As[lc + 1][lr] = av.y;
        As[lc + 2][lr] = av.z; As[lc + 3][lr] = av.w;
        Bs[lc + 0][lr] = bv.x; Bs[lc + 1][lr] = bv.y;
        Bs[lc + 2][lr] = bv.z; Bs[lc + 3][lr] = bv.w;
        __syncthreads();
#pragma unroll
        for (int kk = 0; kk < 8; ++kk) {
            float a[8], bb[8];
#pragma unroll
            for (int i = 0; i < 8; ++i) a[i] = As[kk][ty * 8 + i];
#pragma unroll
            for (int jj = 0; jj < 8; ++jj) bb[jj] = Bs[kk][tx * 8 + jj];
#pragma unroll
            for (int i = 0; i < 8; ++i)
#pragma unroll
                for (int jj = 0; jj < 8; ++jj) acc[i][jj] += a[i] * bb[jj];
        }
    }

    float bxa[8];
#pragma unroll
    for (int jj = 0; jj < 8; ++jj) bxa[jj] = bx[n0 + tx * 8 + jj];
#pragma unroll
    for (int i = 0; i < 8; ++i) {
        float* orow = xg + (size_t)(m0 + ty * 8 + i) * G7 + n0 + tx * 8;
        *(float4*)(orow)     = make_float4(acc[i][0] + bxa[0], acc[i][1] + bxa[1],
                                           acc[i][2] + bxa[2], acc[i][3] + bxa[3]);
        *(float4*)(orow + 4) = make_float4(acc[i][4] + bxa[4], acc[i][5] + bxa[5],
                                           acc[i][6] + bxa[6], acc[i][7] + bxa[7]);
    }
}

// ---------------------------------------------------------------------------
// Kernel 3: recurrence, register-resident fp16 weights.
// 4 blocks per batch (s = h-quarter), 448 threads = 7 waves (one per gate).
// Thread (g,i): row = g*256 + s*64 + i; 128 VGPRs of packed-half2 weights.
// h kept as fp16 in LDS (broadcast reads); 4-way handshake via agent atomics.
// ---------------------------------------------------------------------------
__global__ __launch_bounds__(448, 2) void ctlstm_rec3(
    const float* __restrict__ xg, const float* __restrict__ dt,
    const int* __restrict__ seq_lens, const uint4* __restrict__ Wp,
    const float* __restrict__ bh, float* __restrict__ hx,
    int* __restrict__ cnt, float* __restrict__ out)
{
    __shared__ alignas(16) _Float16 h16[256];   // current h, fp16
    __shared__ float g_lds[448];

    const int bid = blockIdx.x;
    const int b   = bid & 63;        // batch; 4 sub-blocks of b land on XCD b%8
    const int s   = bid >> 6;        // h-quarter 0..3
    const int tid = threadIdx.x;
    const int g   = tid >> 6;        // gate = wave id (0..6), wave-uniform
    const int i   = tid & 63;
    const int row = g * 256 + s * 64 + i;
    const int sl  = seq_lens[b];

    // One-time weight load -> 128 VGPRs (static indexing, fully unrolled)
    uint32_t wvu[128];
#pragma unroll
    for (int c = 0; c < 32; ++c) {
        uint4 t = Wp[(size_t)c * 1792 + row];
        wvu[4 * c + 0] = t.x; wvu[4 * c + 1] = t.y;
        wvu[4 * c + 2] = t.z; wvu[4 * c + 3] = t.w;
    }
    const float bhr = bh[row];
    if (tid < 32) ((uint4*)h16)[tid] = make_uint4(0, 0, 0, 0);
    float cn = 0.f;                  // c-state, valid for tid<64
    __syncthreads();

    for (int t = 0; t < sl; ++t) {
        const float xgv = xg[((size_t)b * SEQL + t) * G7 + row];
        const float dtv = dt[b * SEQL + t];

        // matvec: 128 x v_dot2_f32_f16, 4 parallel accumulators
        float a0 = 0.f, a1 = 0.f, a2 = 0.f, a3 = 0.f;
        const uint4* h4 = (const uint4*)h16;
#pragma unroll
        for (int c = 0; c < 32; ++c) {
            uint4 hv = h4[c];        // broadcast (same addr all lanes)
            a0 = fd2(wvu[4 * c + 0], hv.x, a0);
            a1 = fd2(wvu[4 * c + 1], hv.y, a1);
            a2 = fd2(wvu[4 * c + 2], hv.z, a2);
            a3 = fd2(wvu[4 * c + 3], hv.w, a3);
        }
        const float acc = (a0 + a1) + (a2 + a3) + xgv + bhr;

        float act;
        if (g == 2)      act = tanhf(acc);                                   // z
        else if (g == 4) act = fmaxf(acc, 0.f) + log1pf(expf(-fabsf(acc)));  // d
        else             act = 1.f / (1.f + expf(-acc));                     // sig
        g_lds[tid] = act;
        __syncthreads();

        const int par = t & 1;
        if (tid < 64) {              // wave 0: c/h update for h-indices s*64+i
            float iv  = g_lds[i];
            float fv  = g_lds[64 + i];
            float zv  = g_lds[128 + i];
            float ov  = g_lds[192 + i];
            float dv  = g_lds[256 + i];
            float ibv = g_lds[320 + i];
            float fbv = g_lds[384 + i];

            float c_ = fv * cn + iv * zv;
            float hh = ov * tanhf(c_);
            float cb = fbv * cn + ibv * zv;
            float ct = cb + (c_ - cb) * expf(-dv * dtv);
            float ht = ov * tanhf(ct);
            cn = ct;

            size_t base = ((size_t)b * 513 + t + 1) * 256 + s * 64 + i;
            out[base]                       = ht;
            out[(size_t)OSTRIDE + base]     = hh;
            out[2 * (size_t)OSTRIDE + base] = c_;
            out[3 * (size_t)OSTRIDE + base] = cb;
            out[4 * (size_t)OSTRIDE + base] = ov;
            out[5 * (size_t)OSTRIDE + base] = dv;

            h16[s * 64 + i] = (_Float16)ht;   // own slice, local
            __hip_atomic_store(&hx[(size_t)par * HX_PAR + ((size_t)b * 4 + s) * 64 + i],
                               ht, __ATOMIC_RELAXED, __HIP_MEMORY_SCOPE_AGENT);
        }
        if (tid == 0) {              // same wave as the stores -> release covers them
            __hip_atomic_fetch_add(&cnt[b], 1, __ATOMIC_RELEASE,
                                   __HIP_MEMORY_SCOPE_AGENT);
            while (__hip_atomic_load(&cnt[b], __ATOMIC_ACQUIRE,
                                     __HIP_MEMORY_SCOPE_AGENT) < 4 * (t + 1)) {}
        }
        __syncthreads();

        if (tid >= 64 && tid < 256) {        // waves 1-3: fetch the 3 peer slices
            int p  = (tid >> 6) - 1;         // 0..2
            int ps = p + (p >= s ? 1 : 0);   // peer's s
            float hv = __hip_atomic_load(&hx[(size_t)par * HX_PAR + ((size_t)b * 4 + ps) * 64 + i],
                                         __ATOMIC_RELAXED, __HIP_MEMORY_SCOPE_AGENT);
            h16[ps * 64 + i] = (_Float16)hv;
        }
        __syncthreads();
    }
}

// ---------------------------------------------------------------------------
extern "C" void kernel_launch(void* const* d_in, const int* in_sizes, int n_in,
                              void* d_out, int out_size, void* d_ws, size_t ws_size,
                              hipStream_t stream) {
    const float* x   = (const float*)d_in[0];
    const float* dt  = (const float*)d_in[1];
    const int*   sl  = (const int*)d_in[2];
    const float* Wx  = (const float*)d_in[3];
    const float* bx  = (const float*)d_in[4];
    const float* Wh  = (const float*)d_in[5];
    const float* bh  = (const float*)d_in[6];
    float* out = (float*)d_out;

    float* xg   = (float*)d_ws;
    float* hx   = (float*)((char*)d_ws + HX_OFF);
    int*   cnt  = (int*)((char*)d_ws + CNT_OFF);
    uint4* Wp16 = (uint4*)((char*)d_ws + WP_OFF);

    zero_sync<<<1, 64, 0, stream>>>(cnt);

    int n4 = out_size / 4;
    zero_out<<<2048, 256, 0, stream>>>((float4*)out, n4);

    pack_wh16<<<224, 256, 0, stream>>>(Wh, Wp16);

    dim3 ggrid(G7 / 128, (BATCH * SEQL) / 128);
    gemm_xg<<<ggrid, 256, 0, stream>>>(x, Wx, bx, sl, xg);

    ctlstm_rec3<<<BATCH * 4, 448, 0, stream>>>(xg, dt, sl, Wp16, bh, hx, cnt, out);
}

// Round 4
// 1505.194 us; speedup vs baseline: 6.8812x; 2.2138x over previous
//
#include <hip/hip_runtime.h>
#include <cstddef>
#include <cstdint>

// Problem constants
#define BATCH 64
#define SEQL  512
#define G7    1792            // 7*H
#define OSTRIDE (64*513*256)  // per-output-tensor elements
#define XG_BYTES ((size_t)BATCH*SEQL*G7*4)     // 234,881,024
// ws layout: [xg | hx (2*64*4*64 u32 = 128KB) | Wp16 (918KB)]
#define HX_OFF   XG_BYTES
#define HX_BYTES ((size_t)2*64*4*64*4)
#define WP_OFF   (HX_OFF + HX_BYTES)
#define HX_PAR   16384        // u32 per parity buffer

typedef _Float16 f16x2 __attribute__((ext_vector_type(2)));
union U32H2 { uint32_t u; f16x2 h; };

__device__ __forceinline__ float fd2(uint32_t w, uint32_t h, float c) {
    U32H2 a; a.u = w; U32H2 b; b.u = h;
    return __builtin_amdgcn_fdot2(a.h, b.h, c, false);
}

// ---------------------------------------------------------------------------
__global__ void zero_out(float4* __restrict__ p, int n4) {
    int i = blockIdx.x * blockDim.x + threadIdx.x;
    int stride = gridDim.x * blockDim.x;
    for (; i < n4; i += stride) p[i] = make_float4(0.f, 0.f, 0.f, 0.f);
}

// ---------------------------------------------------------------------------
// Pack Wh (7H x H fp32) -> fp16, uint4 Wp[c][row]: chunk c holds k=8c..8c+7.
// ---------------------------------------------------------------------------
__global__ __launch_bounds__(256) void pack_wh16(const float* __restrict__ Wh,
                                                 uint4* __restrict__ Wp) {
    int idx = blockIdx.x * 256 + threadIdx.x;    // 0 .. 57343
    if (idx >= 1792 * 32) return;
    int r = idx % 1792;
    int c = idx / 1792;
    const float* src = Wh + (size_t)r * 256 + c * 8;
    uint32_t w[4];
#pragma unroll
    for (int j = 0; j < 4; ++j) {
        U32H2 t;
        t.h[0] = (_Float16)src[2 * j];
        t.h[1] = (_Float16)src[2 * j + 1];
        w[j] = t.u;
    }
    Wp[(size_t)c * 1792 + r] = make_uint4(w[0], w[1], w[2], w[3]);
}

// ---------------------------------------------------------------------------
// Kernel 2: xg = x @ Wx^T + bx   (unchanged)
// ---------------------------------------------------------------------------
__global__ __launch_bounds__(256) void gemm_xg(const float* __restrict__ X,
                                               const float* __restrict__ W,
                                               const float* __restrict__ bx,
                                               const int* __restrict__ seq_lens,
                                               float* __restrict__ xg) {
    __shared__ float As[8][132];
    __shared__ float Bs[8][132];
    const int m0 = blockIdx.y * 128;
    const int n0 = blockIdx.x * 128;
    const int b  = m0 >> 9;
    if ((m0 & 511) >= seq_lens[b]) return;

    const int tid = threadIdx.x;
    const int lr  = tid >> 1;
    const int lc  = (tid & 1) << 2;
    const int tx  = tid & 15;
    const int ty  = tid >> 4;

    const float* Aptr = X + (size_t)(m0 + lr) * 256 + lc;
    const float* Bptr = W + (size_t)(n0 + lr) * 256 + lc;

    float acc[8][8] = {};

    for (int k0 = 0; k0 < 256; k0 += 8) {
        float4 av = *(const float4*)(Aptr + k0);
        float4 bv = *(const float4*)(Bptr + k0);
        __syncthreads();
        As[lc + 0][lr] = av.x; As[lc + 1][lr] = av.y;
        As[lc + 2][lr] = av.z; As[lc + 3][lr] = av.w;
        Bs[lc + 0][lr] = bv.x; Bs[lc + 1][lr] = bv.y;
        Bs[lc + 2][lr] = bv.z; Bs[lc + 3][lr] = bv.w;
        __syncthreads();
#pragma unroll
        for (int kk = 0; kk < 8; ++kk) {
            float a[8], bb[8];
#pragma unroll
            for (int i = 0; i < 8; ++i) a[i] = As[kk][ty * 8 + i];
#pragma unroll
            for (int jj = 0; jj < 8; ++jj) bb[jj] = Bs[kk][tx * 8 + jj];
#pragma unroll
            for (int i = 0; i < 8; ++i)
#pragma unroll
                for (int jj = 0; jj < 8; ++jj) acc[i][jj] += a[i] * bb[jj];
        }
    }

    float bxa[8];
#pragma unroll
    for (int jj = 0; jj < 8; ++jj) bxa[jj] = bx[n0 + tx * 8 + jj];
#pragma unroll
    for (int i = 0; i < 8; ++i) {
        float* orow = xg + (size_t)(m0 + ty * 8 + i) * G7 + n0 + tx * 8;
        *(float4*)(orow)     = make_float4(acc[i][0] + bxa[0], acc[i][1] + bxa[1],
                                           acc[i][2] + bxa[2], acc[i][3] + bxa[3]);
        *(float4*)(orow + 4) = make_float4(acc[i][4] + bxa[4], acc[i][5] + bxa[5],
                                           acc[i][6] + bxa[6], acc[i][7] + bxa[7]);
    }
}

// ---------------------------------------------------------------------------
// Kernel 3: recurrence, PINNED register-resident fp16 weights + tagged
// self-validating h-exchange.
// 4 blocks per batch (s = h-quarter), 448 threads = 7 waves (one per gate).
// Thread (g,i): row = g*256 + s*64 + i; 128 VGPRs of packed half2 weights,
// pinned via asm so the compiler cannot re-load them per step.
// Publish: lane i of wave 0 stores (h_fp16 << 16 | (t+1)) agent-scope;
// peer waves poll the word itself until the tag matches (parity dbuf).
// ---------------------------------------------------------------------------
__global__ __launch_bounds__(448, 2) void ctlstm_rec4(
    const float* __restrict__ xg, const float* __restrict__ dt,
    const int* __restrict__ seq_lens, const uint4* __restrict__ Wp,
    const float* __restrict__ bh, uint32_t* __restrict__ hx,
    float* __restrict__ out)
{
    __shared__ alignas(16) _Float16 h16[256];   // current h, fp16
    __shared__ float g_lds[448];

    const int bid = blockIdx.x;
    const int b   = bid & 63;        // sibling blocks {b,b+64,b+128,b+192}: same XCD
    const int s   = bid >> 6;        // h-quarter 0..3
    const int tid = threadIdx.x;
    const int g   = tid >> 6;        // gate = wave id (0..6), wave-uniform
    const int i   = tid & 63;
    const int row = g * 256 + s * 64 + i;
    const int sl  = seq_lens[b];

    // One-time weight load -> 128 VGPRs, then PIN via asm (cannot rematerialize)
    uint32_t wvu[128];
#pragma unroll
    for (int c = 0; c < 32; ++c) {
        uint4 t = Wp[(size_t)c * 1792 + row];
        wvu[4 * c + 0] = t.x; wvu[4 * c + 1] = t.y;
        wvu[4 * c + 2] = t.z; wvu[4 * c + 3] = t.w;
    }
#pragma unroll
    for (int c = 0; c < 32; ++c) {
        asm volatile("" : "+v"(wvu[4 * c + 0]), "+v"(wvu[4 * c + 1]),
                          "+v"(wvu[4 * c + 2]), "+v"(wvu[4 * c + 3]));
    }

    const float bhr = bh[row];
    if (tid < 32) ((uint4*)h16)[tid] = make_uint4(0, 0, 0, 0);
    float cn = 0.f;                  // c-state, valid for wave 0
    // software-pipelined xg/dt loads
    float xc  = xg[((size_t)b * SEQL) * G7 + row];
    float dtc = dt[b * SEQL];
    __syncthreads();

    for (int t = 0; t < sl; ++t) {
        // issue next-step loads early (latency hides under this step)
        const int tn = (t + 1 < sl) ? t + 1 : t;
        float xn  = xg[((size_t)b * SEQL + tn) * G7 + row];
        float dtn = dt[b * SEQL + tn];

        // matvec: 128 x v_dot2_f32_f16, 4 parallel accumulators
        float a0 = 0.f, a1 = 0.f, a2 = 0.f, a3 = 0.f;
        const uint4* h4 = (const uint4*)h16;
#pragma unroll
        for (int c = 0; c < 32; ++c) {
            uint4 hv = h4[c];        // broadcast (same addr all lanes)
            a0 = fd2(wvu[4 * c + 0], hv.x, a0);
            a1 = fd2(wvu[4 * c + 1], hv.y, a1);
            a2 = fd2(wvu[4 * c + 2], hv.z, a2);
            a3 = fd2(wvu[4 * c + 3], hv.w, a3);
        }
        const float acc = (a0 + a1) + (a2 + a3) + xc + bhr;

        float act;
        if (g == 2)      act = tanhf(acc);                                   // z
        else if (g == 4) act = fmaxf(acc, 0.f) + log1pf(expf(-fabsf(acc)));  // d
        else             act = 1.f / (1.f + expf(-acc));                     // sig
        g_lds[tid] = act;
        __syncthreads();                       // B1

        const int par = t & 1;
        const uint32_t want = (uint32_t)(t + 1);
        if (g == 0) {                // wave 0: c/h update for h-indices s*64+i
            float iv  = g_lds[i];
            float fv  = g_lds[64 + i];
            float zv  = g_lds[128 + i];
            float ov  = g_lds[192 + i];
            float dv  = g_lds[256 + i];
            float ibv = g_lds[320 + i];
            float fbv = g_lds[384 + i];

            float c_ = fv * cn + iv * zv;
            float hh = ov * tanhf(c_);
            float cb = fbv * cn + ibv * zv;
            float ct = cb + (c_ - cb) * expf(-dv * dtc);
            float ht = ov * tanhf(ct);
            cn = ct;

            _Float16 hhalf = (_Float16)ht;
            h16[s * 64 + i] = hhalf;           // own slice, local

            // fused publish: data + tag in one word (relaxed, agent scope)
            uint32_t pubv = ((uint32_t)__builtin_bit_cast(unsigned short, hhalf) << 16) | want;
            __hip_atomic_store(&hx[(size_t)par * HX_PAR + ((size_t)b * 4 + s) * 64 + i],
                               pubv, __ATOMIC_RELAXED, __HIP_MEMORY_SCOPE_AGENT);

            size_t base = ((size_t)b * 513 + t + 1) * 256 + s * 64 + i;
            out[base]                       = ht;
            out[(size_t)OSTRIDE + base]     = hh;
            out[2 * (size_t)OSTRIDE + base] = c_;
            out[3 * (size_t)OSTRIDE + base] = cb;
            out[4 * (size_t)OSTRIDE + base] = ov;
            out[5 * (size_t)OSTRIDE + base] = dv;
        } else if (g <= 3) {         // waves 1-3: poll one peer slice each
            int p  = g - 1;
            int ps = p + (p >= s ? 1 : 0);     // peer's quarter
            const uint32_t* src = &hx[(size_t)par * HX_PAR + ((size_t)b * 4 + ps) * 64 + i];
            uint32_t v;
            do {
                v = __hip_atomic_load(src, __ATOMIC_RELAXED, __HIP_MEMORY_SCOPE_AGENT);
            } while (!__all((v & 0xFFFFu) == want));
            h16[ps * 64 + i] = __builtin_bit_cast(_Float16, (unsigned short)(v >> 16));
        }
        __syncthreads();                       // B2: h16 complete

        xc = xn; dtc = dtn;
    }
}

// ---------------------------------------------------------------------------
extern "C" void kernel_launch(void* const* d_in, const int* in_sizes, int n_in,
                              void* d_out, int out_size, void* d_ws, size_t ws_size,
                              hipStream_t stream) {
    const float* x   = (const float*)d_in[0];
    const float* dt  = (const float*)d_in[1];
    const int*   sl  = (const int*)d_in[2];
    const float* Wx  = (const float*)d_in[3];
    const float* bx  = (const float*)d_in[4];
    const float* Wh  = (const float*)d_in[5];
    const float* bh  = (const float*)d_in[6];
    float* out = (float*)d_out;

    float*    xg   = (float*)d_ws;
    uint32_t* hx   = (uint32_t*)((char*)d_ws + HX_OFF);
    uint4*    Wp16 = (uint4*)((char*)d_ws + WP_OFF);

    int n4 = out_size / 4;
    zero_out<<<2048, 256, 0, stream>>>((float4*)out, n4);

    pack_wh16<<<224, 256, 0, stream>>>(Wh, Wp16);

    dim3 ggrid(G7 / 128, (BATCH * SEQL) / 128);
    gemm_xg<<<ggrid, 256, 0, stream>>>(x, Wx, bx, sl, xg);

    // NOTE: hx needs no pre-zeroing — poison tag 0xAAAA never matches 1..512,
    // and parity slots self-validate per step.
    ctlstm_rec4<<<BATCH * 4, 448, 0, stream>>>(xg, dt, sl, Wp16, bh, hx, out);
}